// Round 10
// baseline (185.568 us; speedup 1.0000x reference)
//
#include <hip/hip_runtime.h>
#include <hip/hip_bf16.h>
#include <stdint.h>

// Problem constants
#define B_   2
#define T_   2048
#define D_   1024
#define H_   16
#define HD_  64
#define MEM_ 512
#define KV_  (MEM_ + T_)   // 2560
#define NIT_ (KV_ / 64)    // 40 kv-tiles of 64
#define NIT2_ (NIT_ / 2)   // 20 per kv-half

using bf16 = __bf16;
typedef __bf16 bf16x8 __attribute__((ext_vector_type(8)));
typedef float  f32x4  __attribute__((ext_vector_type(4)));
typedef short  s16x4  __attribute__((ext_vector_type(4)));
typedef short  s16x8  __attribute__((ext_vector_type(8)));

__device__ __forceinline__ f32x4 mfma16(bf16x8 a, bf16x8 b, f32x4 c) {
  return __builtin_amdgcn_mfma_f32_16x16x32_bf16(a, b, c, 0, 0, 0);
}

// Async global->LDS, 16B per lane (dest = wave-uniform base + lane*16).
__device__ __forceinline__ void gll16(const void* g, void* l) {
  __builtin_amdgcn_global_load_lds(
      (const __attribute__((address_space(1))) unsigned int*)g,
      (__attribute__((address_space(3))) unsigned int*)l, 16, 0, 0);
}

__device__ __forceinline__ unsigned short bf16_bits(float f) {
  bf16 h = (bf16)f;
  return __builtin_bit_cast(unsigned short, h);
}

__device__ __forceinline__ ushort4 pack4(f32x4 v) {
  ushort4 p;
  p.x = bf16_bits(v[0]); p.y = bf16_bits(v[1]);
  p.z = bf16_bits(v[2]); p.w = bf16_bits(v[3]);
  return p;
}

__device__ __forceinline__ bf16x8 cvt8(f32x4 a, f32x4 b) {
  bf16x8 r;
  r[0] = (bf16)a[0]; r[1] = (bf16)a[1]; r[2] = (bf16)a[2]; r[3] = (bf16)a[3];
  r[4] = (bf16)b[0]; r[5] = (bf16)b[1]; r[6] = (bf16)b[2]; r[7] = (bf16)b[3];
  return r;
}

// V^T kv-column permutation within each 64-aligned tile: u = 16g+4c+r
// stored at pos = (g>>1)*32 + c*8 + (g&1)*4 + r.  Makes PV's two 4-elem
// pieces ADJACENT 16B in LDS -> single b128 read (R9: conflicts -98.8%).
__device__ __forceinline__ int vperm4(int u) {   // u multiple of 4
  int g = u >> 4, c = (u >> 2) & 3;
  return (g >> 1) * 32 + c * 8 + (g & 1) * 4;
}

// ---------------------------------------------------------------------------
// prep (fused): blk 0-2047 x conv | 2048-3583 w_qkv conv |
//   3584-3839 memory -> mem_k | 3840-4095 memory -> mem_vt (permuted) |
//   4096-4607 w_out conv (only when ws has room).
// ---------------------------------------------------------------------------
__global__ void prep(const float* __restrict__ x, const float* __restrict__ wq,
                     const float* __restrict__ memory,
                     const float* __restrict__ wout,
                     bf16* __restrict__ xb, bf16* __restrict__ wqb,
                     bf16* __restrict__ mem_k, bf16* __restrict__ mem_vt,
                     bf16* __restrict__ wob) {
  int blk = blockIdx.x;
  if (blk < 3584) {
    const float* s = (blk < 2048) ? x : wq;
    bf16* d = (blk < 2048) ? xb : wqb;
    size_t i = ((size_t)(blk < 2048 ? blk : blk - 2048) * 256 + threadIdx.x) * 8;
    f32x4 a = *(const f32x4*)(s + i);
    f32x4 b = *(const f32x4*)(s + i + 4);
    *(bf16x8*)(d + i) = cvt8(a, b);
  } else if (blk < 3840) {
    int idx8 = ((blk - 3584) * 256 + threadIdx.x) * 8;   // [0, 512*1024)
    int m = idx8 >> 10, d0 = idx8 & 1023;
    int hh = d0 >> 6, hd0 = d0 & 63;
    f32x4 a = *(const f32x4*)(memory + idx8);
    f32x4 b = *(const f32x4*)(memory + idx8 + 4);
    *(bf16x8*)&mem_k[((size_t)hh * MEM_ + m) * HD_ + hd0] = cvt8(a, b);
  } else if (blk < 4096) {
    int idx = (blk - 3840) * 256 + threadIdx.x;          // [0, 65536)
    int d = idx & 1023;
    int m0 = (idx >> 10) * 8;                            // 0..511 step 8
    bf16x8 r;
#pragma unroll
    for (int j = 0; j < 8; j++)
      r[j] = (bf16)memory[(size_t)(m0 + j) * D_ + d];
    // permuted store: groups (g,c) and (g,c+1) land at pos and pos+8
    int u = m0 & 63;
    bf16* dst = &mem_vt[(size_t)d * MEM_ + (m0 - u) + vperm4(u)];
    s16x8 rb = __builtin_bit_cast(s16x8, r);
    *(s16x4*)dst = __builtin_shufflevector(rb, rb, 0, 1, 2, 3);
    *(s16x4*)(dst + 8) = __builtin_shufflevector(rb, rb, 4, 5, 6, 7);
  } else {
    size_t i = ((size_t)(blk - 4096) * 256 + threadIdx.x) * 8;
    f32x4 a = *(const f32x4*)(wout + i);
    f32x4 b = *(const f32x4*)(wout + i + 4);
    *(bf16x8*)(wob + i) = cvt8(a, b);
  }
}

// w_out conv fallback: runs AFTER attn (dest aliases k_ws, dead by then).
__global__ void conv_bf16(const float* __restrict__ s, bf16* __restrict__ d) {
  size_t i = ((size_t)blockIdx.x * 256 + threadIdx.x) * 8;
  f32x4 a = *(const f32x4*)(s + i);
  f32x4 b = *(const f32x4*)(s + i + 4);
  *(bf16x8*)(d + i) = cvt8(a, b);
}

// ---------------------------------------------------------------------------
// gemm256: QKV projection at 256x256 tile, 8 waves (2M x 4N), BK=64,
// COUNTED-vmcnt pipeline (same proven discipline as the attn stage loop):
//   stage tile t+1's 8 gll16 FIRST, then s_waitcnt vmcnt(8) -> only tile t's
//   loads are drained; t+1's stay in flight across the barrier.
// Per wave: 64 MFMA between barrier pairs (2x the 128^2 kernel), A-panel
// LDS reads shared by 4 waves.  LDS 128 KB (2 buf x (A 32K + B 32K)),
// 1 block/CU, VGPR ~200 under the (512,2) cap of 256.
// Same both-sides XOR chunk swizzle; scatter epilogue (q/k planes, vperm'd
// v^T) re-indexed for the 2x4 wave grid.  C = A[4096,1024] * W[3072,1024]^T.
// ---------------------------------------------------------------------------
__global__ __launch_bounds__(512, 2) void gemm256(
    const bf16* __restrict__ A, const bf16* __restrict__ W,
    bf16* __restrict__ q_ws, bf16* __restrict__ k_ws,
    bf16* __restrict__ vt_ws, int K) {
  __shared__ __align__(16) bf16 Als[2 * 256 * 64];   // 64 KB
  __shared__ __align__(16) bf16 Bls[2 * 256 * 64];   // 64 KB
  char* AB = (char*)Als;
  char* BB = (char*)Bls;
  // Bijective XCD swizzle (nwg = 12*16 = 192, 192 % 8 == 0).
  const int nwg = gridDim.x * gridDim.y;
  int lin = blockIdx.y * gridDim.x + blockIdx.x;
  lin = (lin & 7) * (nwg >> 3) + (lin >> 3);
  const int m0 = (lin / gridDim.x) * 256;
  const int n0 = (lin % gridDim.x) * 256;
  const int tid = threadIdx.x;         // 0..511
  const int wid = tid >> 6;
  const int wr = wid >> 2;             // 0..1  (M)
  const int wc = wid & 3;              // 0..3  (N)
  const int lane = tid & 63;
  const int lx = lane & 15;
  const int quad = lane >> 4;
  const int srow = tid >> 3;                    // 0..63
  const int cs = (tid & 7) ^ (srow & 7);        // swizzled source chunk

  // Stage K-tile t into buffer bi: 4 gll (A rows g*64+srow) + 4 gll (B).
  auto stage = [&](int t, int bi) {
    const bf16* pa = A + (size_t)(m0 + srow) * K + t * 64 + cs * 8;
    const bf16* pb = W + (size_t)(n0 + srow) * K + t * 64 + cs * 8;
    char* ad = AB + bi * 32768 + tid * 16;
    char* bd = BB + bi * 32768 + tid * 16;
#pragma unroll
    for (int g = 0; g < 4; g++) {
      gll16(pa + (size_t)(g * 64) * K, ad + g * 8192);
      gll16(pb + (size_t)(g * 64) * K, bd + g * 8192);
    }
  };

  f32x4 acc[8][4];
#pragma unroll
  for (int m = 0; m < 8; m++)
#pragma unroll
    for (int n = 0; n < 4; n++) acc[m][n] = (f32x4){0.f, 0.f, 0.f, 0.f};

  const int rk = (lx & 7) << 4;   // read-side swizzle key (row&7 == lx&7)
  const int nt_steps = K >> 6;    // 16

  stage(0, 0);   // prologue

  for (int t = 0; t < nt_steps; t++) {
    const int buf = t & 1;
    if (t + 1 < nt_steps) {
      stage(t + 1, buf ^ 1);
      asm volatile("s_waitcnt vmcnt(8)" ::: "memory");   // tile t landed
    } else {
      asm volatile("s_waitcnt vmcnt(0)" ::: "memory");
    }
    __builtin_amdgcn_s_barrier();
    __builtin_amdgcn_sched_barrier(0);

    const char* AT = AB + buf * 32768;
    const char* BT = BB + buf * 32768;

    bf16x8 bfr[4][2];
#pragma unroll
    for (int n = 0; n < 4; n++)
#pragma unroll
      for (int kh = 0; kh < 2; kh++)
        bfr[n][kh] = *(const bf16x8*)(BT +
            (size_t)(wc * 64 + n * 16 + lx) * 128 +
            ((quad * 16 + kh * 64) ^ rk));

    __builtin_amdgcn_s_setprio(1);
#pragma unroll
    for (int m = 0; m < 8; m++) {
      const char* ar = AT + (size_t)(wr * 128 + m * 16 + lx) * 128;
      bf16x8 af0 = *(const bf16x8*)(ar + ((quad * 16) ^ rk));
      bf16x8 af1 = *(const bf16x8*)(ar + ((quad * 16 + 64) ^ rk));
#pragma unroll
      for (int n = 0; n < 4; n++) {
        acc[m][n] = mfma16(af0, bfr[n][0], acc[m][n]);
        acc[m][n] = mfma16(af1, bfr[n][1], acc[m][n]);
      }
    }
    __builtin_amdgcn_s_setprio(0);

    __builtin_amdgcn_sched_barrier(0);
    __builtin_amdgcn_s_barrier();   // reads of buf done before re-stage
  }

  // Scatter epilogue.  C/D layout: row = quad*4+reg, col = lane&15.
#pragma unroll
  for (int m = 0; m < 8; m++) {
    int mbase = m0 + wr * 128 + m * 16 + quad * 4;
    int b = mbase >> 11;        // T=2048
    int tt = mbase & 2047;
#pragma unroll
    for (int n = 0; n < 4; n++) {
      int col = n0 + wc * 64 + n * 16 + lx;    // [0,3072)
      int which = col >> 10;                   // 0=q 1=k 2=v
      int d = col & 1023;
      int hh = d >> 6, hdi = d & 63;
      int bh = b * H_ + hh;
      if (which == 0) {
#pragma unroll
        for (int r = 0; r < 4; r++)
          q_ws[((size_t)bh * T_ + tt + r) * HD_ + hdi] = (bf16)acc[m][n][r];
      } else if (which == 1) {
#pragma unroll
        for (int r = 0; r < 4; r++)
          k_ws[((size_t)bh * T_ + tt + r) * HD_ + hdi] = (bf16)acc[m][n][r];
      } else {
        int u = tt & 63;
        *(ushort4*)&vt_ws[((size_t)bh * HD_ + hdi) * T_ + (tt - u) +
                          vperm4(u)] = pack4(acc[m][n]);
      }
    }
  }
}

// ---------------------------------------------------------------------------
// gemm_bt (kept for the out-projection): 128 x NTILE tile, BK=64, 4 waves.
// EPI==1: bias add -> Cout f32.  APLANE: A is plane layout [bh][t][64].
// ---------------------------------------------------------------------------
template <int EPI, bool APLANE, int NTILE>
__global__ __launch_bounds__(256, 3) void gemm_bt(
    const bf16* __restrict__ A, const bf16* __restrict__ W,
    const float* __restrict__ bias,
    bf16* __restrict__ q_ws, bf16* __restrict__ k_ws, bf16* __restrict__ vt_ws,
    float* __restrict__ Cout, int K) {
  constexpr int NF = NTILE / 32;
  constexpr int NB = NTILE / 32;
  __shared__ __align__(16) bf16 Als[128 * 64];
  __shared__ __align__(16) bf16 Bls[NTILE * 64];
  char* AB = (char*)Als;
  char* BB = (char*)Bls;
  const int nwg = gridDim.x * gridDim.y;
  int lin = blockIdx.y * gridDim.x + blockIdx.x;
  lin = (lin & 7) * (nwg >> 3) + (lin >> 3);
  const int m0 = (lin / gridDim.x) * 128;
  const int n0 = (lin % gridDim.x) * NTILE;
  const int tid = threadIdx.x;
  const int w = tid >> 6;
  const int lane = tid & 63;
  const int lx = lane & 15;
  const int quad = lane >> 4;
  const int amb = (w & 1) * 64;
  const int bnb = (w >> 1) * (NTILE / 2);
  const int srow = tid >> 3;
  const int cs = (tid & 7) ^ (srow & 7);

  f32x4 acc[4][NF];
#pragma unroll
  for (int i = 0; i < 4; i++)
#pragma unroll
    for (int j = 0; j < NF; j++) acc[i][j] = (f32x4){0.f, 0.f, 0.f, 0.f};

  for (int k0 = 0; k0 < K; k0 += 64) {
    const bf16* pa[4];
#pragma unroll
    for (int g = 0; g < 4; g++) {
      int r = srow + 32 * g;
      if constexpr (APLANE) {
        int hh = k0 >> 6, hd = cs * 8;
        int mA = m0 + r;
        pa[g] = A + ((size_t)((mA >> 11) * H_ + hh) * T_ + (mA & 2047)) * HD_ + hd;
      } else {
        pa[g] = A + (size_t)(m0 + r) * K + k0 + cs * 8;
      }
    }
    const bf16* pb[NB];
#pragma unroll
    for (int g = 0; g < NB; g++)
      pb[g] = W + (size_t)(n0 + srow + 32 * g) * K + k0 + cs * 8;

    __syncthreads();
#pragma unroll
    for (int g = 0; g < 4; g++) gll16(pa[g], AB + g * 4096 + tid * 16);
#pragma unroll
    for (int g = 0; g < NB; g++) gll16(pb[g], BB + g * 4096 + tid * 16);
    __syncthreads();

    bf16x8 af[4][2], bfr[NF][2];
    const int rk = (lx & 7) << 4;
#pragma unroll
    for (int mt = 0; mt < 4; mt++)
#pragma unroll
      for (int kh = 0; kh < 2; kh++)
        af[mt][kh] = *(const bf16x8*)(AB + (size_t)(amb + mt * 16 + lx) * 128 +
                                      ((quad * 16 + kh * 64) ^ rk));
#pragma unroll
    for (int nt = 0; nt < NF; nt++)
#pragma unroll
      for (int kh = 0; kh < 2; kh++)
        bfr[nt][kh] = *(const bf16x8*)(BB + (size_t)(bnb + nt * 16 + lx) * 128 +
                                       ((quad * 16 + kh * 64) ^ rk));
#pragma unroll
    for (int kh = 0; kh < 2; kh++)
#pragma unroll
      for (int mt = 0; mt < 4; mt++)
#pragma unroll
        for (int nt = 0; nt < NF; nt++)
          acc[mt][nt] = mfma16(af[mt][kh], bfr[nt][kh], acc[mt][nt]);
  }

  if (EPI == 0) {
    // unused in this configuration (gemm256 handles QKV)
  } else {
#pragma unroll
    for (int nt = 0; nt < NF; nt++) {
      int col = n0 + bnb + nt * 16 + lx;
      float bias_f = bias[col];
#pragma unroll
      for (int mt = 0; mt < 4; mt++) {
        int mbase = m0 + amb + mt * 16 + quad * 4;
#pragma unroll
        for (int r = 0; r < 4; r++)
          Cout[(size_t)(mbase + r) * D_ + col] = acc[mt][nt][r] + bias_f;
      }
    }
  }
}

// ---------------------------------------------------------------------------
// Flash attention (R9 structure, frozen): kv-split x2, 512 threads, b128 PV
// via vperm4, ones-MFMA row-sum, counted vmcnt, linear kv-half merge.
// ---------------------------------------------------------------------------
__global__ __launch_bounds__(512, 4) void attn_kernel(
    bf16* __restrict__ q_ws, const bf16* __restrict__ k_ws,
    const bf16* __restrict__ vt_ws, const bf16* __restrict__ mem_k,
    const bf16* __restrict__ mem_vt) {
  __shared__ __align__(16) bf16 Kls[2 * 2 * 64 * 64];   // [half][buf] 32 KB
  __shared__ __align__(16) bf16 Vls[2 * 2 * 64 * 64];   // [half][buf] 32 KB
  char* KB = (char*)Kls;
  char* VB = (char*)Vls;
  const int tid = threadIdx.x;         // 0..511
  const int wh = tid >> 8;             // kv-half
  const int t2 = tid & 255;
  const int w = t2 >> 6;               // wave within half
  const int lane = tid & 63;
  const int lx = lane & 15;
  const int quad = lane >> 4;
  const int bh = blockIdx.x & 31;      // XCD-locality
  const int qt = blockIdx.x >> 5;      // 16 q-tiles of 128
  const int q0 = qt * 128 + w * 32;
  const int h = bh & 15;

  const int srow1 = t2 >> 3;               // 0..31
  const int sc1 = (t2 & 7) ^ (srow1 & 7);  // pre-swizzled source chunk

  char* KBh = KB + wh * 16384;
  char* VBh = VB + wh * 16384;

  bf16* qbase = q_ws + ((size_t)bh * T_ + q0) * HD_;

  const bf16* kpl = k_ws + (size_t)bh * T_ * HD_;
  const bf16* vpl = vt_ws + (size_t)bh * HD_ * T_;
  const bf16* mkp = mem_k + (size_t)h * MEM_ * HD_;   // per-head plane
  const bf16* mvp = mem_vt + (size_t)h * HD_ * MEM_;

  auto stage = [&](int it2, int bi) {
    const int kv0 = (wh * NIT2_ + it2) * 64;
    const bf16 *kp1, *kp2, *vp1, *vp2;
    if (kv0 < MEM_) {
      kp1 = mkp + (size_t)(kv0 + srow1) * HD_ + sc1 * 8;
      kp2 = kp1 + (size_t)32 * HD_;
      vp1 = mvp + (size_t)srow1 * MEM_ + kv0 + sc1 * 8;
      vp2 = vp1 + (size_t)32 * MEM_;
    } else {
      const int t0 = kv0 - MEM_;
      kp1 = kpl + (size_t)(t0 + srow1) * HD_ + sc1 * 8;
      kp2 = kp1 + (size_t)32 * HD_;
      vp1 = vpl + (size_t)srow1 * T_ + t0 + sc1 * 8;
      vp2 = vp1 + (size_t)32 * T_;
    }
    char* kb = KBh + bi * 8192;
    char* vb = VBh + bi * 8192;
    gll16(kp1, kb + t2 * 16);
    gll16(kp2, kb + t2 * 16 + 4096);
    gll16(vp1, vb + t2 * 16);
    gll16(vp2, vb + t2 * 16 + 4096);
  };

  const float QSCALE = 0.125f * 1.44269504089f;
  bf16x8 qf[2][2];
#pragma unroll
  for (int qg = 0; qg < 2; qg++)
#pragma unroll
    for (int hf = 0; hf < 2; hf++) {
      bf16x8 v = *(const bf16x8*)(qbase + (size_t)(qg * 16 + lx) * HD_ +
                                  hf * 32 + quad * 8);
#pragma unroll
      for (int i = 0; i < 8; i++)
        v[i] = (bf16)((float)v[i] * QSCALE);
      qf[qg][hf] = v;
    }

  bf16x8 ones;
#pragma unroll
  for (int i = 0; i < 8; i++) ones[i] = (bf16)1.0f;

  f32x4 o[4][2];
#pragma unroll
  for (int mt = 0; mt < 4; mt++)
#pragma unroll
    for (int qg = 0; qg < 2; qg++) o[mt][qg] = (f32x4){0.f, 0.f, 0.f, 0.f};
  f32x4 osum[2] = {(f32x4){0.f, 0.f, 0.f, 0.f}, (f32x4){0.f, 0.f, 0.f, 0.f}};

  stage(0, 0);

  for (int it = 0; it < NIT2_; it++) {
    const int cur = it & 1;
    if (it + 1 < NIT2_) {
      stage(it + 1, cur ^ 1);
      asm volatile("s_waitcnt vmcnt(4)" ::: "memory");
    } else {
      asm volatile("s_waitcnt vmcnt(0)" ::: "memory");
    }
    __builtin_amdgcn_s_barrier();
    __builtin_amdgcn_sched_barrier(0);

    const char* KBc = KBh + cur * 8192;
    const char* VBc = VBh + cur * 8192;
    const int sw = (lx & 7) << 4;
    f32x4 s[4][2];
    __builtin_amdgcn_s_setprio(1);
#pragma unroll
    for (int g = 0; g < 4; g++) {
      const char* kb = KBc + (size_t)(g * 16 + lx) * 128;
      bf16x8 ka0 = *(const bf16x8*)(kb + ((quad * 16) ^ sw));
      bf16x8 ka1 = *(const bf16x8*)(kb + ((64 + quad * 16) ^ sw));
#pragma unroll
      for (int qg = 0; qg < 2; qg++) {
        s[g][qg] = (f32x4){0.f, 0.f, 0.f, 0.f};
        s[g][qg] = mfma16(ka0, qf[qg][0], s[g][qg]);
        s[g][qg] = mfma16(ka1, qf[qg][1], s[g][qg]);
      }
    }
    __builtin_amdgcn_s_setprio(0);

    s16x8 pk[2][2];
#pragma unroll
    for (int qg = 0; qg < 2; qg++) {
#pragma unroll
      for (int g = 0; g < 4; g++) {
#pragma unroll
        for (int r = 0; r < 4; r++) {
          float p = __builtin_amdgcn_exp2f(s[g][qg][r]);
          pk[qg][g >> 1][(g & 1) * 4 + r] = (short)bf16_bits(p);
        }
      }
    }

    __builtin_amdgcn_s_setprio(1);
#pragma unroll
    for (int mt = 0; mt < 4; mt++) {
      const char* vb = VBc + (size_t)(mt * 16 + lx) * 128;
#pragma unroll
      for (int p = 0; p < 2; p++) {
        bf16x8 va = *(const bf16x8*)(vb + ((p * 64 + quad * 16) ^ sw));
#pragma unroll
        for (int qg = 0; qg < 2; qg++)
          o[mt][qg] = mfma16(va, __builtin_bit_cast(bf16x8, pk[qg][p]),
                             o[mt][qg]);
      }
    }
#pragma unroll
    for (int p = 0; p < 2; p++)
#pragma unroll
      for (int qg = 0; qg < 2; qg++)
        osum[qg] = mfma16(ones, __builtin_bit_cast(bf16x8, pk[qg][p]),
                          osum[qg]);
    __builtin_amdgcn_s_setprio(0);

    __builtin_amdgcn_sched_barrier(0);
    __builtin_amdgcn_s_barrier();
  }

  float* OS = (float*)KB;
  float* OSS = (float*)VB;
  if (wh == 1) {
    float* dst = OS + t2 * 32;
#pragma unroll
    for (int mt = 0; mt < 4; mt++)
#pragma unroll
      for (int qg = 0; qg < 2; qg++) {
        int c = mt * 2 + qg;
        *(f32x4*)(dst + ((c ^ (t2 & 7)) * 4)) = o[mt][qg];
      }
    OSS[t2 * 2 + 0] = osum[0][0];
    OSS[t2 * 2 + 1] = osum[1][0];
  }
  __syncthreads();
  if (wh == 0) {
    const float* src = OS + t2 * 32;
    float inv[2] = {1.f / (osum[0][0] + OSS[t2 * 2 + 0]),
                    1.f / (osum[1][0] + OSS[t2 * 2 + 1])};
#pragma unroll
    for (int qg = 0; qg < 2; qg++) {
#pragma unroll
      for (int mt = 0; mt < 4; mt++) {
        int c = mt * 2 + qg;
        f32x4 po = *(const f32x4*)(src + ((c ^ (t2 & 7)) * 4));
        f32x4 ov;
#pragma unroll
        for (int r = 0; r < 4; r++) ov[r] = (o[mt][qg][r] + po[r]) * inv[qg];
        *(ushort4*)(qbase + (size_t)(qg * 16 + lx) * HD_ + mt * 16 + quad * 4)
            = pack4(ov);
      }
    }
  }
}

// ---------------------------------------------------------------------------
// Scratch plan (unchanged):
//   ws:    q_ws 0-8M | k_ws 8-16M | vt_ws 16-24M | mem_k 24-25M | mem_vt 25-26M
//          | wob 26-28M (if ws_size >= 28M; else wob aliases k_ws post-attn)
//   d_out: xb 0-8M | wqb 8-14M  [dead after gemm256; gemm2 overwrites d_out]
// ---------------------------------------------------------------------------
extern "C" void kernel_launch(void* const* d_in, const int* in_sizes, int n_in,
                              void* d_out, int out_size, void* d_ws,
                              size_t ws_size, hipStream_t stream) {
  const float* x      = (const float*)d_in[0];   // [B,T,D]   f32
  const float* w_qkv  = (const float*)d_in[1];   // [3D,D]    f32
  const float* w_out  = (const float*)d_in[2];   // [D,D]     f32
  const float* b_out  = (const float*)d_in[3];   // [D]       f32
  const float* memory = (const float*)d_in[4];   // [MEM,D]   f32

  char* ws = (char*)d_ws;
  bf16* q_ws   = (bf16*)(ws);                    // [32][2048][64]  8 MiB
  bf16* k_ws   = (bf16*)(ws + (8u << 20));       // [32][2048][64]  8 MiB
  bf16* vt_ws  = (bf16*)(ws + (16u << 20));      // [32][64][2048]  8 MiB
  bf16* mem_k  = (bf16*)(ws + (24u << 20));      // [16][512][64]   1 MiB
  bf16* mem_vt = (bf16*)(ws + (25u << 20));      // [1024][512]     1 MiB
  float* out = (float*)d_out;                    // f32 per reference

  char* outc = (char*)d_out;
  bf16* xb  = (bf16*)(outc);                     // 8 MiB scratch in d_out
  bf16* wqb = (bf16*)(outc + (8u << 20));        // 6 MiB scratch in d_out

  const bool big_ws = ws_size >= (28u << 20);
  bf16* wob = big_ws ? (bf16*)(ws + (26u << 20))   // private 2 MiB
                     : (bf16*)(ws + (8u << 20));   // aliases k_ws (post-attn)

  prep<<<dim3(big_ws ? 4608 : 4096), dim3(256), 0, stream>>>(
      x, w_qkv, memory, w_out, xb, wqb, mem_k, mem_vt, wob);
  gemm256<<<dim3(12, 16), dim3(512), 0, stream>>>(
      xb, wqb, q_ws, k_ws, vt_ws, 1024);
  attn_kernel<<<dim3(512), dim3(512), 0, stream>>>(
      q_ws, k_ws, vt_ws, mem_k, mem_vt);
  if (!big_ws)
    conv_bf16<<<dim3(512), dim3(256), 0, stream>>>(w_out, wob);
  gemm_bt<1, true, 64><<<dim3(16, 32), dim3(256), 0, stream>>>(
      q_ws, wob, b_out, nullptr, nullptr, nullptr, out, 1024);
}